// Round 11
// baseline (309.371 us; speedup 1.0000x reference)
//
#include <hip/hip_runtime.h>

// Problem constants (from reference)
#define Bx 4
#define Nn 10000
#define Ee 160000
#define Qq 256
#define Dd 128
#define Mm 64
#define Uu 126
#define Hh 128
#define Pp 7

// N padded to groups of 8 (1250 groups) + 2 pad groups for ragged K-tail
#define KG 1252

typedef unsigned short u16;
typedef __bf16 bf16x8 __attribute__((ext_vector_type(8)));
typedef float f32x4 __attribute__((ext_vector_type(4)));

__device__ __forceinline__ float b2f(u16 h){
  unsigned u = ((unsigned)h) << 16; float f; __builtin_memcpy(&f, &u, 4); return f;
}
// hardware RNE f32->bf16
__device__ __forceinline__ u16 f2b(float f){
  __bf16 h = (__bf16)f; u16 r; __builtin_memcpy(&r, &h, 2); return r;
}
__device__ __forceinline__ float ldin(const void* p, long i, int flag){
  return flag ? b2f(((const u16*)p)[i]) : ((const float*)p)[i];
}

// ---------------- inline dtype probe (per-wave ballot; replaces probe_kernel) ----------------
__device__ __forceinline__ int detect_flag(const void* in0){
  int lane = threadIdx.x & 63;
  const u16* p = (const u16*)in0;
  int c = 0;
  #pragma unroll
  for (int j = 0; j < 4; j++){
    float a = fabsf(b2f(p[lane * 4 + j]));
    c += (a > 0.0009765625f && a < 32.0f) ? 1 : 0;
  }
  #pragma unroll
  for (int o = 32; o; o >>= 1) c += __shfl_xor(c, o, 64);
  return c >= 240;
}

// ---------------- fused weight prep + state init (bf16 only, vectorized) + degree count ----------------
// v24: NO f32 state master (verified R10: absmax 0.0234, passes).
// w2e swizzle keeps the pi(k) = (k&15)*8 + (k>>4) permutation (v20-validated).
__global__ void prep_init_kernel(const void* w1e, const void* b1e, const void* w2e, const void* b2e,
                                 const void* w1n, const void* b1n, const void* w2n, const void* b2n,
                                 const void* in0, const int* __restrict__ snk,
                                 u16* w1e_s, u16* w2e_s, u16* w1n_s, u16* w2n_s,
                                 float* b1e_f, float* b2e_f, float* b1n_f, float* b2n_f,
                                 u16* __restrict__ sbm, int* __restrict__ cnt)
{
  int f = detect_flag(in0);
  long gsz = (long)gridDim.x * blockDim.x;
  long base = (long)blockIdx.x * blockDim.x + threadIdx.x;
  // weights
  for (long idx = base; idx < 82368; idx += gsz){
    if (idx < 32768){                                   // w1e (256,128)
      int k = (int)idx >> 7, h = (int)idx & 127;
      w1e_s[(k >> 3) * 1024 + h * 8 + (k & 7)] = f2b(ldin(w1e, idx, f));
    } else if (idx < 40960){                            // w2e (128,64), pi on k
      int i2 = (int)idx - 32768; int k = i2 >> 6, m2 = i2 & 63;
      w2e_s[(k & 15) * 512 + m2 * 8 + (k >> 4)] = f2b(ldin(w2e, i2, f));
    } else if (idx < 65536){                            // w1n (192,128)
      int i2 = (int)idx - 40960; int k = i2 >> 7, h = i2 & 127;
      w1n_s[(k >> 3) * 1024 + h * 8 + (k & 7)] = f2b(ldin(w1n, i2, f));
    } else if (idx < 81920){                            // w2n (128,126) padded to 128 cols
      int i2 = (int)idx - 65536; int k = i2 >> 7, u = i2 & 127;
      float v = (u < 126) ? ldin(w2n, (long)k * 126 + u, f) : 0.f;
      w2n_s[(k >> 3) * 1024 + u * 8 + (k & 7)] = f2b(v);
    } else if (idx < 82048){ b1e_f[idx - 81920] = ldin(b1e, idx - 81920, f); }
    else if (idx < 82112){ b2e_f[idx - 82048] = ldin(b2e, idx - 82048, f); }
    else if (idx < 82240){ b1n_f[idx - 82112] = ldin(b1n, idx - 82112, f); }
    else { int j = (int)idx - 82240; b2n_f[j] = (j < 126) ? ldin(b2n, j, f) : 0.f; }
  }
  // states -> bf16 mirror, 8 elems/thread
  const long total8 = (long)Bx * Nn * Dd / 8;
  for (long i = base; i < total8; i += gsz){
    if (f){
      *(uint4*)(sbm + i * 8) = *(const uint4*)((const u16*)in0 + i * 8);
    } else {
      const float* ip = (const float*)in0 + i * 8;
      float4 a = *(const float4*)ip;
      float4 b2 = *(const float4*)(ip + 4);
      union { u16 h[8]; uint4 v; } t;
      t.h[0] = f2b(a.x); t.h[1] = f2b(a.y); t.h[2] = f2b(a.z); t.h[3] = f2b(a.w);
      t.h[4] = f2b(b2.x); t.h[5] = f2b(b2.y); t.h[6] = f2b(b2.z); t.h[7] = f2b(b2.w);
      *(uint4*)(sbm + i * 8) = t.v;
    }
  }
  // sink-degree histogram
  for (long i = base; i < Ee; i += gsz)
    atomicAdd(&cnt[snk[(int)i]], 1);
}

// ---------------- CSR build ----------------
__global__ void scan_kernel(const int* __restrict__ cnt, int* __restrict__ rowp){
  __shared__ int tot[1024];
  int t = threadIdx.x;
  int base = t * 10;
  int local[10]; int s = 0;
  #pragma unroll
  for (int i = 0; i < 10; i++){
    int v = (base + i < Nn) ? cnt[base + i] : 0;
    local[i] = s; s += v;
  }
  tot[t] = s;
  __syncthreads();
  for (int o = 1; o < 1024; o <<= 1){
    int v = (t >= o) ? tot[t - o] : 0;
    __syncthreads();
    tot[t] += v;
    __syncthreads();
  }
  int prefix = (t == 0) ? 0 : tot[t - 1];
  #pragma unroll
  for (int i = 0; i < 10; i++)
    if (base + i < Nn) rowp[base + i] = prefix + local[i];
  if (t == 1023) rowp[Nn] = tot[1023];
}

// ---------------- fused CSR fill + step-0 xform (independent work, one dispatch) ----------------
// Blocks [0,625): fill (625*256 == Ee exactly). Blocks [625,1257): xform.
// xform: Xa[n]=s@W1a+b1, Xb[n]=s@W1b, pi-order register-local 16B stores.
__global__ __launch_bounds__(256) void fill_xform_kernel(
  const int* __restrict__ src, const int* __restrict__ snk,
  const int* __restrict__ rowp, int* __restrict__ cnt, int* __restrict__ psrc,
  const u16* __restrict__ sbm, const u16* __restrict__ w1s,
  const float* __restrict__ b1f, u16* __restrict__ xab)
{
  __shared__ __align__(16) u16 w1h[16384];     // 32KB: one K-half of w1e, swizzled
  int tid = threadIdx.x;
  if (blockIdx.x < 625){
    int i = blockIdx.x * 256 + tid;
    int s = snk[i];
    int p = rowp[s] + atomicAdd(&cnt[s], 1);
    psrc[p] = src[i];
    return;
  }
  int xbid = blockIdx.x - 625;
  int b = (xbid & 7) >> 1;
  int nt = ((xbid >> 3) << 1) + (xbid & 1);
  if (nt >= 157) return;                       // uniform per block; before any barrier
  int n0 = nt * 64;
  int w = tid >> 6, lane = tid & 63, m = lane & 15, quad = lane >> 4;
  int n = n0 + w * 16 + m;
  int nld = n < Nn ? n : Nn - 1;
  const u16* srow = sbm + (((size_t)b * Nn + nld) << 7);

  bf16x8 a[4];
  #pragma unroll
  for (int lk = 0; lk < 4; lk++) a[lk] = *(const bf16x8*)(srow + lk * 32 + quad * 8);

  const f32x4 z4 = {0.f, 0.f, 0.f, 0.f};
  float bb[8];
  #pragma unroll
  for (int ct = 0; ct < 8; ct++) bb[ct] = b1f[ct * 16 + m];

  #pragma unroll
  for (int half = 0; half < 2; half++){
    __syncthreads();                           // prior w1h readers done
    {
      const uint4* g = (const uint4*)(w1s + half * 16384);
      uint4* l = (uint4*)w1h;
      #pragma unroll
      for (int i = 0; i < 8; i++) l[tid + i * 256] = g[tid + i * 256];
    }
    __syncthreads();
    f32x4 acc[8];
    #pragma unroll
    for (int ct = 0; ct < 8; ct++) acc[ct] = z4;
    #pragma unroll
    for (int lk = 0; lk < 4; lk++){
      #pragma unroll
      for (int ct = 0; ct < 8; ct++){
        bf16x8 bv = *(const bf16x8*)(w1h + (((lk * 4 + quad) << 7) + ct * 16 + m) * 8);
        acc[ct] = __builtin_amdgcn_mfma_f32_16x16x32_bf16(a[lk], bv, acc[ct], 0, 0, 0);
      }
    }
    #pragma unroll
    for (int i = 0; i < 4; i++){
      int r = n0 + w * 16 + quad * 4 + i;
      if (r < Nn){
        union { u16 h[8]; uint4 v; } t;
        #pragma unroll
        for (int ct = 0; ct < 8; ct++)
          t.h[ct] = f2b(acc[ct][i] + ((half == 0) ? bb[ct] : 0.f));
        *(uint4*)(xab + ((size_t)b * Nn + r) * 256 + half * 128 + m * 8) = t.v;
      }
    }
  }
}

// ---------------- node v24: v17 gather core (FROZEN) + fused next-xform / swz, NO sf ----------------
// incoming[n] = (Σ_{e→n} relu(Xa[src]+Xb[n])) @ W2e + deg(n)*b2e (linearity fusion).
// GATHER FLOOR evidence v13-v21 (do not re-attempt): unroll/prefetch, chain
// split, oversub, coalescing (-3.5%), 2x occupancy+deg-sort (null), residency/
// nontemporal (regressed), fp8 (regressed), 4 indep loads/trip (null).
// v24: f32 master DELETED (verified R10). mode==0: epilogue -> sbm + state tile
// -> fused next-step xform -> xabn. mode==1: state tile -> sswz transposed.
__global__ __launch_bounds__(256) void node_kernel(
  u16* __restrict__ sbm, const u16* __restrict__ xab,
  const int* __restrict__ rowp, const int* __restrict__ psrc,
  const u16* __restrict__ w2es, const float* __restrict__ b2ef,
  const u16* __restrict__ w1s, const u16* __restrict__ w2s,
  const float* __restrict__ b1f, const float* __restrict__ b2f2,
  const u16* __restrict__ w1es, const float* __restrict__ b1ef,
  u16* __restrict__ xabn, u16* __restrict__ sswz, int mode)
{
  __shared__ __align__(16) u16 ninp[64 * 200];   // phase1/3 input; then W1 quarter staging
  __shared__ __align__(16) u16 hsYt[64 * 136];   // phase2 A-op, phase3 Yt, then state tile
  int b = (blockIdx.x & 7) >> 1;
  int nt = ((blockIdx.x >> 3) << 1) + (blockIdx.x & 1);
  if (nt >= 157) return;
  int n0 = nt * 64;
  int tid = threadIdx.x;

  // ---- phase 1: hsum[n] = Σ relu(Xa[src]+Xb[n]) over in-edges; states -> ninp ----
  {
    int nl = tid >> 2, part = tid & 3;
    int n = n0 + nl;
    float acc[32];
    #pragma unroll
    for (int i = 0; i < 32; i++) acc[i] = 0.f;
    if (n < Nn){
      float xbf[32];
      {
        const u16* xp = xab + ((size_t)b * Nn + n) * 256 + 128 + part * 8;
        union { uint4 v; u16 h[8]; } q0, q1, q2, q3;
        q0.v = *(const uint4*)(xp);
        q1.v = *(const uint4*)(xp + 32);
        q2.v = *(const uint4*)(xp + 64);
        q3.v = *(const uint4*)(xp + 96);
        #pragma unroll
        for (int j = 0; j < 8; j++){
          xbf[j] = b2f(q0.h[j]); xbf[8 + j] = b2f(q1.h[j]);
          xbf[16 + j] = b2f(q2.h[j]); xbf[24 + j] = b2f(q3.h[j]);
        }
      }
      int r0 = rowp[n], r1 = rowp[n + 1];
      const u16* xb0 = xab + (size_t)b * Nn * 256 + part * 8;
      for (int r = r0; r < r1; r++){
        int s = psrc[r];
        const u16* xs = xb0 + (size_t)s * 256;
        union { uint4 v; u16 h[8]; } q0, q1, q2, q3;
        q0.v = *(const uint4*)(xs);
        q1.v = *(const uint4*)(xs + 32);
        q2.v = *(const uint4*)(xs + 64);
        q3.v = *(const uint4*)(xs + 96);
        #pragma unroll
        for (int j = 0; j < 8; j++){
          float v0 = b2f(q0.h[j]) + xbf[j];
          acc[j] += v0 > 0.f ? v0 : 0.f;
          float v1 = b2f(q1.h[j]) + xbf[8 + j];
          acc[8 + j] += v1 > 0.f ? v1 : 0.f;
          float v2 = b2f(q2.h[j]) + xbf[16 + j];
          acc[16 + j] += v2 > 0.f ? v2 : 0.f;
          float v3 = b2f(q3.h[j]) + xbf[24 + j];
          acc[24 + j] += v3 > 0.f ? v3 : 0.f;
        }
      }
    }
    // write hs row (bf16, pi-space) — consumed by this wave's phase-2 MFMA.
    union { u16 h[32]; uint4 v[4]; } hb;
    #pragma unroll
    for (int i = 0; i < 32; i++) hb.h[i] = f2b(acc[i]);
    u16* hp = hsYt + nl * 136 + part * 8;
    *(uint4*)(hp)      = hb.v[0];
    *(uint4*)(hp + 32) = hb.v[1];
    *(uint4*)(hp + 64) = hb.v[2];
    *(uint4*)(hp + 96) = hb.v[3];
    // states part of ninp (same lane-contiguous pattern)
    u16* dp = ninp + nl * 200 + 64 + part * 8;
    if (n < Nn){
      const u16* sp = sbm + (((size_t)b * Nn + n) << 7) + part * 8;
      *(uint4*)(dp)      = *(const uint4*)(sp);
      *(uint4*)(dp + 32) = *(const uint4*)(sp + 32);
      *(uint4*)(dp + 64) = *(const uint4*)(sp + 64);
      *(uint4*)(dp + 96) = *(const uint4*)(sp + 96);
    } else {
      uint4 zz = {0, 0, 0, 0};
      *(uint4*)(dp)      = zz;
      *(uint4*)(dp + 32) = zz;
      *(uint4*)(dp + 64) = zz;
      *(uint4*)(dp + 96) = zz;
    }
  }
  // no barrier: wave w wrote hs/ninp rows [16w,16w+16) and reads only those below

  int w = tid >> 6, lane = tid & 63, m = lane & 15, quad = lane >> 4;
  const f32x4 z4 = {0.f, 0.f, 0.f, 0.f};

  // ---- phase 2: incoming = hs @ w2e + deg*b2e -> ninp[0:64] ----
  // hs and w2es both pi-ordered on k -> contraction unchanged.
  {
    f32x4 acc[4];
    #pragma unroll
    for (int ct = 0; ct < 4; ct++) acc[ct] = z4;
    #pragma unroll
    for (int ks = 0; ks < 4; ks++){
      bf16x8 a = *(const bf16x8*)(hsYt + (w * 16 + m) * 136 + ks * 32 + quad * 8);
      #pragma unroll
      for (int ct = 0; ct < 4; ct++){
        bf16x8 bv = *(const bf16x8*)(w2es + (((ks * 4 + quad) << 6) + ct * 16 + m) * 8);
        acc[ct] = __builtin_amdgcn_mfma_f32_16x16x32_bf16(a, bv, acc[ct], 0, 0, 0);
      }
    }
    #pragma unroll
    for (int i = 0; i < 4; i++){
      int n = n0 + w * 16 + quad * 4 + i;
      float deg = (n < Nn) ? (float)(rowp[n + 1] - rowp[n]) : 0.f;
      #pragma unroll
      for (int ct = 0; ct < 4; ct++)
        ninp[(w * 16 + quad * 4 + i) * 200 + ct * 16 + m] = f2b(acc[ct][i] + deg * b2ef[ct * 16 + m]);
    }
  }

  // ---- phase 3: node MLP ----
  f32x4 acc1[8];
  #pragma unroll
  for (int ct = 0; ct < 8; ct++) acc1[ct] = z4;
  #pragma unroll 1
  for (int ks = 0; ks < 6; ks++){
    bf16x8 a = *(const bf16x8*)(ninp + (w * 16 + m) * 200 + ks * 32 + quad * 8);
    #pragma unroll
    for (int ct = 0; ct < 8; ct++){
      bf16x8 bv = *(const bf16x8*)(w1s + (((ks * 4 + quad) << 7) + ct * 16 + m) * 8);
      acc1[ct] = __builtin_amdgcn_mfma_f32_16x16x32_bf16(a, bv, acc1[ct], 0, 0, 0);
    }
  }
  #pragma unroll
  for (int ct = 0; ct < 8; ct++){
    float bb = b1f[ct * 16 + m];
    #pragma unroll
    for (int i = 0; i < 4; i++){
      float v = acc1[ct][i] + bb;
      v = v > 0.f ? v : 0.f;
      hsYt[(w * 16 + quad * 4 + i) * 136 + ct * 16 + m] = f2b(v);
    }
  }
  f32x4 acc2[8];
  #pragma unroll
  for (int ct = 0; ct < 8; ct++) acc2[ct] = z4;
  #pragma unroll 1
  for (int ko = 0; ko < 4; ko++){
    bf16x8 a2 = *(const bf16x8*)(hsYt + (w * 16 + m) * 136 + ko * 32 + quad * 8);
    #pragma unroll
    for (int ct = 0; ct < 8; ct++){
      bf16x8 bv = *(const bf16x8*)(w2s + (((ko * 4 + quad) << 7) + ct * 16 + m) * 8);
      acc2[ct] = __builtin_amdgcn_mfma_f32_16x16x32_bf16(a2, bv, acc2[ct], 0, 0, 0);
    }
  }

  // ---- phase 4: epilogue. Old state = ninp LDS (no global read). Build new-state
  // tile in hsYt (wave-private rows). mode==0 additionally writes the sbm mirror. ----
  #pragma unroll
  for (int ct = 0; ct < 8; ct++){
    int u = ct * 16 + m;
    if (u < 126){
      float bb = b2f2[u];
      #pragma unroll
      for (int i = 0; i < 4; i++){
        int nl = w * 16 + quad * 4 + i;
        int n = n0 + nl;
        if (n < Nn){
          float old = b2f(ninp[nl * 200 + 64 + 2 + u]);
          float v = old + acc2[ct][i] + bb;
          u16 hv = f2b(v);
          if (mode == 0)
            sbm[(((size_t)b * Nn + n) << 7) + 2 + u] = hv;
          hsYt[nl * 136 + 2 + u] = hv;
        } else {
          hsYt[nl * 136 + 2 + u] = 0;
        }
      }
    }
  }
  // channels 0,1 are never updated: copy old state (0 for pad rows) from ninp
  if (m < 2){
    #pragma unroll
    for (int i = 0; i < 4; i++){
      int nl = w * 16 + quad * 4 + i;
      hsYt[nl * 136 + m] = ninp[nl * 200 + 64 + m];
    }
  }

  if (mode == 0){
    // ---- fused next-step xform: Xa/Xb = newstate @ W1e, pi-order stores ----
    // W1 staged in 16KB quarters (64 k-rows) into dead ninp region.
    #pragma unroll
    for (int half = 0; half < 2; half++){
      f32x4 xacc[8];
      #pragma unroll
      for (int ct = 0; ct < 8; ct++) xacc[ct] = z4;
      #pragma unroll
      for (int st = 0; st < 2; st++){
        __syncthreads();                       // tile/ch01 writes + prior staging reads done
        {
          const uint4* g = (const uint4*)(w1es + half * 16384 + st * 8192);
          uint4* l = (uint4*)ninp;
          #pragma unroll
          for (int i = 0; i < 4; i++) l[tid + i * 256] = g[tid + i * 256];
        }
        __syncthreads();
        #pragma unroll
        for (int lk = 0; lk < 2; lk++){
          bf16x8 a = *(const bf16x8*)(hsYt + (w * 16 + m) * 136 + st * 64 + lk * 32 + quad * 8);
          #pragma unroll
          for (int ct = 0; ct < 8; ct++){
            bf16x8 bv = *(const bf16x8*)(ninp + (((lk * 4 + quad) << 7) + ct * 16 + m) * 8);
            xacc[ct] = __builtin_amdgcn_mfma_f32_16x16x32_bf16(a, bv, xacc[ct], 0, 0, 0);
          }
        }
      }
      #pragma unroll
      for (int i = 0; i < 4; i++){
        int r = n0 + w * 16 + quad * 4 + i;
        if (r < Nn){
          union { u16 h[8]; uint4 v; } t;
          #pragma unroll
          for (int ct = 0; ct < 8; ct++)
            t.h[ct] = f2b(xacc[ct][i] + ((half == 0) ? b1ef[ct * 16 + m] : 0.f));
          *(uint4*)(xabn + ((size_t)b * Nn + r) * 256 + half * 128 + m * 8) = t.v;
        }
      }
    }
  } else {
    // ---- last step: wave-private transposed store to sswz (kg planes nt*8+2w+{0,1}) ----
    #pragma unroll
    for (int r = 0; r < 2; r++){
      int kg = nt * 8 + w * 2 + r;
      if (kg < KG){
        #pragma unroll
        for (int dd = 0; dd < 2; dd++){
          int d = dd * 64 + lane;
          union { u16 h[8]; uint4 v; } t;
          #pragma unroll
          for (int j = 0; j < 8; j++) t.h[j] = hsYt[(w * 16 + r * 8 + j) * 136 + d];
          *(uint4*)(sswz + (((size_t)b * KG + kg) * 128 + d) * 8) = t.v;
        }
      }
    }
  }
}

// ---------------- extraction v25: LDS-staged B (block-shared), 63 chunks ----------------
// Old: each wave issued 8 dependent 16B L2 loads/step from sswz (4 waves/block
// read IDENTICAL data -> 4-8x redundant L2 traffic at 200-500cyc latency,
// 2 blocks/CU). v25: 63 chunks x 20 kg; block stages its 40KB sswz slice into
// LDS once (coalesced), all 4 waves ds_read B-frags. 1008 blocks = 4/CU.
// Tail chunk 62: 12 kg, 3 steps. A-zero guard for kg>=1250 kept (OOB attn).
__global__ __launch_bounds__(256) void extract2_kernel(
  const void* __restrict__ attn, const void* __restrict__ in_states,
  const u16* __restrict__ sswz, float* __restrict__ partsum)
{
  __shared__ __align__(16) u16 bstage[20 * 1024];   // 40KB
  int f = detect_flag(in_states);
  int blk = blockIdx.x;
  int kc = blk % 63; int rest = blk / 63;
  int qt = rest & 3, b = rest >> 2;
  int tid = threadIdx.x, w = tid >> 6, lane = tid & 63, m = lane & 15, quad = lane >> 4;
  int qr = qt * 4 + w, q0 = qr * 16;
  int kg0 = kc * 20;
  int nsteps = (kc == 62) ? 3 : 5;
  int valid = (kc == 62) ? 12 : 20;                 // staged kg count
  // stage: valid*128 uint4, coalesced
  {
    const uint4* src = (const uint4*)(sswz + ((size_t)b * KG + kg0) * 1024);
    int nv = valid * 128;
    #pragma unroll
    for (int k = 0; k < 10; k++){
      int idx = tid + k * 256;
      if (idx < nv) ((uint4*)bstage)[idx] = src[idx];
    }
  }
  __syncthreads();

  long arow = ((long)(b * Qq + q0 + m)) * Nn;
  const u16* ab16 = (const u16*)attn + arow;
  const float* af32 = (const float*)attn + arow;
  f32x4 acc[8];
  const f32x4 z4 = {0.f, 0.f, 0.f, 0.f};
  #pragma unroll
  for (int ct = 0; ct < 8; ct++) acc[ct] = z4;
  #pragma unroll 2
  for (int t = 0; t < nsteps; t++){
    int lkg = t * 4 + quad;
    int kg = kg0 + lkg;
    bf16x8 a;
    if (kg < 1250){
      if (f){
        a = *(const bf16x8*)(ab16 + kg * 8);
      } else {
        const float* ap = af32 + kg * 8;
        float4 p0 = *(const float4*)ap;
        float4 p1 = *(const float4*)(ap + 4);
        a[0] = (__bf16)p0.x; a[1] = (__bf16)p0.y; a[2] = (__bf16)p0.z; a[3] = (__bf16)p0.w;
        a[4] = (__bf16)p1.x; a[5] = (__bf16)p1.y; a[6] = (__bf16)p1.z; a[7] = (__bf16)p1.w;
      }
    } else {
      #pragma unroll
      for (int j = 0; j < 8; j++) a[j] = (__bf16)0.f;
    }
    const u16* bb = bstage + lkg * 1024;
    #pragma unroll
    for (int ct = 0; ct < 8; ct++){
      bf16x8 bv = *(const bf16x8*)(bb + (ct * 16 + m) * 8);
      acc[ct] = __builtin_amdgcn_mfma_f32_16x16x32_bf16(a, bv, acc[ct], 0, 0, 0);
    }
  }
  #pragma unroll
  for (int ct = 0; ct < 8; ct++){
    #pragma unroll
    for (int i = 0; i < 4; i++)
      atomicAdd(&partsum[(((size_t)b * Qq + q0 + quad * 4 + i) << 7) + ct * 16 + m], acc[ct][i]);
  }
}

// ---------------- finalize: out = [poses | partsum] ----------------
__global__ void final_kernel(const void* __restrict__ poses, const void* __restrict__ in_states,
                             const float* __restrict__ partsum, void* __restrict__ out)
{
  int f = detect_flag(in_states);
  const long total = (long)Bx * Qq * (Pp + Dd);
  for (long idx = (long)blockIdx.x * blockDim.x + threadIdx.x; idx < total; idx += (long)gridDim.x * blockDim.x){
    int j = (int)(idx % (Pp + Dd));
    long bq = idx / (Pp + Dd);
    float v;
    if (j < Pp){
      v = ldin(poses, bq * Pp + j, f);
    } else {
      v = partsum[(bq << 7) + (j - Pp)];
    }
    if (f) ((u16*)out)[idx] = f2b(v);
    else ((float*)out)[idx] = v;
  }
}

extern "C" void kernel_launch(void* const* d_in, const int* in_sizes, int n_in,
                              void* d_out, int out_size, void* d_ws, size_t ws_size,
                              hipStream_t stream)
{
  const void* in_states = d_in[0];
  const void* in_poses  = d_in[1];
  const void* in_attn   = d_in[2];
  const int*  in_src    = (const int*)d_in[3];
  const int*  in_snk    = (const int*)d_in[4];
  const void* in_w1e = d_in[5];  const void* in_b1e = d_in[6];
  const void* in_w2e = d_in[7];  const void* in_b2e = d_in[8];
  const void* in_w1n = d_in[9];  const void* in_b1n = d_in[10];
  const void* in_w2n = d_in[11]; const void* in_b2n = d_in[12];

  char* ws = (char*)d_ws;
  size_t off = 0;
  auto alloc = [&](size_t bytes){ size_t o = off; off = (off + bytes + 255) & ~(size_t)255; return o; };
  const size_t psumB = (size_t)Bx * Qq * Dd * 4;        // 0.5 MB
  size_t o_sb   = alloc((size_t)Bx * Nn * Dd * 2);
  size_t o_xabA = alloc((size_t)Bx * Nn * 256 * 2);     // 20.5 MB double-buffered
  size_t o_xabB = alloc((size_t)Bx * Nn * 256 * 2);
  size_t o_rowp = alloc((size_t)(Nn + 1) * 4);
  size_t o_rcnt = alloc((size_t)Nn * 2 * 4 + psumB);    // rcnt | rcnt2 | partsum: one memset
  size_t o_psrc = alloc((size_t)Ee * 4);
  size_t o_w1e  = alloc(32768 * 2);
  size_t o_w2e  = alloc(8192 * 2);
  size_t o_w1n  = alloc(24576 * 2);
  size_t o_w2n  = alloc(16384 * 2);
  size_t o_b1e  = alloc(128 * 4);
  size_t o_b2e  = alloc(64 * 4);
  size_t o_b1n  = alloc(128 * 4);
  size_t o_b2n  = alloc(128 * 4);
  size_t o_sswz = alloc((size_t)Bx * KG * 128 * 8 * 2); // 10.3 MB

  u16*   sbm   = (u16*)(ws + o_sb);
  u16*   xabA  = (u16*)(ws + o_xabA);
  u16*   xabB  = (u16*)(ws + o_xabB);
  int*   rowp  = (int*)(ws + o_rowp);
  int*   rcnt  = (int*)(ws + o_rcnt);
  int*   rcnt2 = rcnt + Nn;
  float* psum  = (float*)(ws + o_rcnt + (size_t)Nn * 2 * 4);
  int*   psrc  = (int*)(ws + o_psrc);
  u16*   w1e_s = (u16*)(ws + o_w1e);
  u16*   w2e_s = (u16*)(ws + o_w2e);
  u16*   w1n_s = (u16*)(ws + o_w1n);
  u16*   w2n_s = (u16*)(ws + o_w2n);
  float* b1e_f = (float*)(ws + o_b1e);
  float* b2e_f = (float*)(ws + o_b2e);
  float* b1n_f = (float*)(ws + o_b1n);
  float* b2n_f = (float*)(ws + o_b2n);
  u16*   sswz  = (u16*)(ws + o_sswz);

  hipMemsetAsync(rcnt, 0, (size_t)Nn * 2 * 4 + psumB, stream);  // rcnt, rcnt2, partsum
  prep_init_kernel<<<1024, 256, 0, stream>>>(in_w1e, in_b1e, in_w2e, in_b2e,
                                             in_w1n, in_b1n, in_w2n, in_b2n,
                                             in_states, in_snk,
                                             w1e_s, w2e_s, w1n_s, w2n_s,
                                             b1e_f, b2e_f, b1n_f, b2n_f,
                                             sbm, rcnt);
  scan_kernel<<<1, 1024, 0, stream>>>(rcnt, rowp);
  fill_xform_kernel<<<1257, 256, 0, stream>>>(in_src, in_snk, rowp, rcnt2, psrc,
                                              sbm, w1e_s, b1e_f, xabA);

  // step 0: gather xabA, fused xform -> xabB
  node_kernel<<<632, 256, 0, stream>>>(sbm, xabA, rowp, psrc,
                                       w2e_s, b2e_f, w1n_s, w2n_s, b1n_f, b2n_f,
                                       w1e_s, b1e_f, xabB, sswz, 0);
  // step 1: gather xabB, fused xform -> xabA
  node_kernel<<<632, 256, 0, stream>>>(sbm, xabB, rowp, psrc,
                                       w2e_s, b2e_f, w1n_s, w2n_s, b1n_f, b2n_f,
                                       w1e_s, b1e_f, xabA, sswz, 0);
  // step 2 (last): gather xabA, states -> sswz
  node_kernel<<<632, 256, 0, stream>>>(sbm, xabA, rowp, psrc,
                                       w2e_s, b2e_f, w1n_s, w2n_s, b1n_f, b2n_f,
                                       w1e_s, b1e_f, xabB, sswz, 1);

  extract2_kernel<<<1008, 256, 0, stream>>>(in_attn, in_states, sswz, psum);
  final_kernel<<<540, 256, 0, stream>>>(in_poses, in_states, psum, d_out);
}

// Round 12
// 302.271 us; speedup vs baseline: 1.0235x; 1.0235x over previous
//
#include <hip/hip_runtime.h>

// Problem constants (from reference)
#define Bx 4
#define Nn 10000
#define Ee 160000
#define Qq 256
#define Dd 128
#define Mm 64
#define Uu 126
#define Hh 128
#define Pp 7

// N padded to groups of 8 (1250 groups) + 2 pad groups for ragged K-tail
#define KG 1252

typedef unsigned short u16;
typedef __bf16 bf16x8 __attribute__((ext_vector_type(8)));
typedef float f32x4 __attribute__((ext_vector_type(4)));

__device__ __forceinline__ float b2f(u16 h){
  unsigned u = ((unsigned)h) << 16; float f; __builtin_memcpy(&f, &u, 4); return f;
}
// hardware RNE f32->bf16
__device__ __forceinline__ u16 f2b(float f){
  __bf16 h = (__bf16)f; u16 r; __builtin_memcpy(&r, &h, 2); return r;
}
__device__ __forceinline__ float ldin(const void* p, long i, int flag){
  return flag ? b2f(((const u16*)p)[i]) : ((const float*)p)[i];
}

// ---------------- inline dtype probe (per-wave ballot; replaces probe_kernel) ----------------
__device__ __forceinline__ int detect_flag(const void* in0){
  int lane = threadIdx.x & 63;
  const u16* p = (const u16*)in0;
  int c = 0;
  #pragma unroll
  for (int j = 0; j < 4; j++){
    float a = fabsf(b2f(p[lane * 4 + j]));
    c += (a > 0.0009765625f && a < 32.0f) ? 1 : 0;
  }
  #pragma unroll
  for (int o = 32; o; o >>= 1) c += __shfl_xor(c, o, 64);
  return c >= 240;
}

// ---------------- fused weight prep + state init (bf16 only, vectorized) + degree count ----------------
// v24: NO f32 state master (verified R10: absmax 0.0234, passes).
// w2e swizzle keeps the pi(k) = (k&15)*8 + (k>>4) permutation (v20-validated).
__global__ void prep_init_kernel(const void* w1e, const void* b1e, const void* w2e, const void* b2e,
                                 const void* w1n, const void* b1n, const void* w2n, const void* b2n,
                                 const void* in0, const int* __restrict__ snk,
                                 u16* w1e_s, u16* w2e_s, u16* w1n_s, u16* w2n_s,
                                 float* b1e_f, float* b2e_f, float* b1n_f, float* b2n_f,
                                 u16* __restrict__ sbm, int* __restrict__ cnt)
{
  int f = detect_flag(in0);
  long gsz = (long)gridDim.x * blockDim.x;
  long base = (long)blockIdx.x * blockDim.x + threadIdx.x;
  // weights
  for (long idx = base; idx < 82368; idx += gsz){
    if (idx < 32768){                                   // w1e (256,128)
      int k = (int)idx >> 7, h = (int)idx & 127;
      w1e_s[(k >> 3) * 1024 + h * 8 + (k & 7)] = f2b(ldin(w1e, idx, f));
    } else if (idx < 40960){                            // w2e (128,64), pi on k
      int i2 = (int)idx - 32768; int k = i2 >> 6, m2 = i2 & 63;
      w2e_s[(k & 15) * 512 + m2 * 8 + (k >> 4)] = f2b(ldin(w2e, i2, f));
    } else if (idx < 65536){                            // w1n (192,128)
      int i2 = (int)idx - 40960; int k = i2 >> 7, h = i2 & 127;
      w1n_s[(k >> 3) * 1024 + h * 8 + (k & 7)] = f2b(ldin(w1n, i2, f));
    } else if (idx < 81920){                            // w2n (128,126) padded to 128 cols
      int i2 = (int)idx - 65536; int k = i2 >> 7, u = i2 & 127;
      float v = (u < 126) ? ldin(w2n, (long)k * 126 + u, f) : 0.f;
      w2n_s[(k >> 3) * 1024 + u * 8 + (k & 7)] = f2b(v);
    } else if (idx < 82048){ b1e_f[idx - 81920] = ldin(b1e, idx - 81920, f); }
    else if (idx < 82112){ b2e_f[idx - 82048] = ldin(b2e, idx - 82048, f); }
    else if (idx < 82240){ b1n_f[idx - 82112] = ldin(b1n, idx - 82112, f); }
    else { int j = (int)idx - 82240; b2n_f[j] = (j < 126) ? ldin(b2n, j, f) : 0.f; }
  }
  // states -> bf16 mirror, 8 elems/thread
  const long total8 = (long)Bx * Nn * Dd / 8;
  for (long i = base; i < total8; i += gsz){
    if (f){
      *(uint4*)(sbm + i * 8) = *(const uint4*)((const u16*)in0 + i * 8);
    } else {
      const float* ip = (const float*)in0 + i * 8;
      float4 a = *(const float4*)ip;
      float4 b2 = *(const float4*)(ip + 4);
      union { u16 h[8]; uint4 v; } t;
      t.h[0] = f2b(a.x); t.h[1] = f2b(a.y); t.h[2] = f2b(a.z); t.h[3] = f2b(a.w);
      t.h[4] = f2b(b2.x); t.h[5] = f2b(b2.y); t.h[6] = f2b(b2.z); t.h[7] = f2b(b2.w);
      *(uint4*)(sbm + i * 8) = t.v;
    }
  }
  // sink-degree histogram
  for (long i = base; i < Ee; i += gsz)
    atomicAdd(&cnt[snk[(int)i]], 1);
}

// ---------------- CSR build ----------------
__global__ void scan_kernel(const int* __restrict__ cnt, int* __restrict__ rowp){
  __shared__ int tot[1024];
  int t = threadIdx.x;
  int base = t * 10;
  int local[10]; int s = 0;
  #pragma unroll
  for (int i = 0; i < 10; i++){
    int v = (base + i < Nn) ? cnt[base + i] : 0;
    local[i] = s; s += v;
  }
  tot[t] = s;
  __syncthreads();
  for (int o = 1; o < 1024; o <<= 1){
    int v = (t >= o) ? tot[t - o] : 0;
    __syncthreads();
    tot[t] += v;
    __syncthreads();
  }
  int prefix = (t == 0) ? 0 : tot[t - 1];
  #pragma unroll
  for (int i = 0; i < 10; i++)
    if (base + i < Nn) rowp[base + i] = prefix + local[i];
  if (t == 1023) rowp[Nn] = tot[1023];
}

// ---------------- fused CSR fill + step-0 xform (independent work, one dispatch) ----------------
// Blocks [0,625): fill (625*256 == Ee exactly). Blocks [625,1257): xform.
// xform: Xa[n]=s@W1a+b1, Xb[n]=s@W1b, pi-order register-local 16B stores.
__global__ __launch_bounds__(256) void fill_xform_kernel(
  const int* __restrict__ src, const int* __restrict__ snk,
  const int* __restrict__ rowp, int* __restrict__ cnt, int* __restrict__ psrc,
  const u16* __restrict__ sbm, const u16* __restrict__ w1s,
  const float* __restrict__ b1f, u16* __restrict__ xab)
{
  __shared__ __align__(16) u16 w1h[16384];     // 32KB: one K-half of w1e, swizzled
  int tid = threadIdx.x;
  if (blockIdx.x < 625){
    int i = blockIdx.x * 256 + tid;
    int s = snk[i];
    int p = rowp[s] + atomicAdd(&cnt[s], 1);
    psrc[p] = src[i];
    return;
  }
  int xbid = blockIdx.x - 625;
  int b = (xbid & 7) >> 1;
  int nt = ((xbid >> 3) << 1) + (xbid & 1);
  if (nt >= 157) return;                       // uniform per block; before any barrier
  int n0 = nt * 64;
  int w = tid >> 6, lane = tid & 63, m = lane & 15, quad = lane >> 4;
  int n = n0 + w * 16 + m;
  int nld = n < Nn ? n : Nn - 1;
  const u16* srow = sbm + (((size_t)b * Nn + nld) << 7);

  bf16x8 a[4];
  #pragma unroll
  for (int lk = 0; lk < 4; lk++) a[lk] = *(const bf16x8*)(srow + lk * 32 + quad * 8);

  const f32x4 z4 = {0.f, 0.f, 0.f, 0.f};
  float bb[8];
  #pragma unroll
  for (int ct = 0; ct < 8; ct++) bb[ct] = b1f[ct * 16 + m];

  #pragma unroll
  for (int half = 0; half < 2; half++){
    __syncthreads();                           // prior w1h readers done
    {
      const uint4* g = (const uint4*)(w1s + half * 16384);
      uint4* l = (uint4*)w1h;
      #pragma unroll
      for (int i = 0; i < 8; i++) l[tid + i * 256] = g[tid + i * 256];
    }
    __syncthreads();
    f32x4 acc[8];
    #pragma unroll
    for (int ct = 0; ct < 8; ct++) acc[ct] = z4;
    #pragma unroll
    for (int lk = 0; lk < 4; lk++){
      #pragma unroll
      for (int ct = 0; ct < 8; ct++){
        bf16x8 bv = *(const bf16x8*)(w1h + (((lk * 4 + quad) << 7) + ct * 16 + m) * 8);
        acc[ct] = __builtin_amdgcn_mfma_f32_16x16x32_bf16(a[lk], bv, acc[ct], 0, 0, 0);
      }
    }
    #pragma unroll
    for (int i = 0; i < 4; i++){
      int r = n0 + w * 16 + quad * 4 + i;
      if (r < Nn){
        union { u16 h[8]; uint4 v; } t;
        #pragma unroll
        for (int ct = 0; ct < 8; ct++)
          t.h[ct] = f2b(acc[ct][i] + ((half == 0) ? bb[ct] : 0.f));
        *(uint4*)(xab + ((size_t)b * Nn + r) * 256 + half * 128 + m * 8) = t.v;
      }
    }
  }
}

// ---------------- node v24: v17 gather core (FROZEN) + fused next-xform / swz, NO sf ----------------
// incoming[n] = (Σ_{e→n} relu(Xa[src]+Xb[n])) @ W2e + deg(n)*b2e (linearity fusion).
// GATHER FLOOR evidence v13-v21 (do not re-attempt): unroll/prefetch, chain
// split, oversub, coalescing (-3.5%), 2x occupancy+deg-sort (null), residency/
// nontemporal (regressed), fp8 (regressed), 4 indep loads/trip (null).
// v24: f32 master DELETED (verified R10). mode==0: epilogue -> sbm + state tile
// -> fused next-step xform -> xabn. mode==1: state tile -> sswz transposed.
// R11 lesson: extract2 LDS-staging of B REGRESSED (+8us) — scattered L2-hit
// reads are cheaper than latency models predict; don't add traffic to save them.
__global__ __launch_bounds__(256) void node_kernel(
  u16* __restrict__ sbm, const u16* __restrict__ xab,
  const int* __restrict__ rowp, const int* __restrict__ psrc,
  const u16* __restrict__ w2es, const float* __restrict__ b2ef,
  const u16* __restrict__ w1s, const u16* __restrict__ w2s,
  const float* __restrict__ b1f, const float* __restrict__ b2f2,
  const u16* __restrict__ w1es, const float* __restrict__ b1ef,
  u16* __restrict__ xabn, u16* __restrict__ sswz, int mode)
{
  __shared__ __align__(16) u16 ninp[64 * 200];   // phase1/3 input; then W1 quarter staging
  __shared__ __align__(16) u16 hsYt[64 * 136];   // phase2 A-op, phase3 Yt, then state tile
  int b = (blockIdx.x & 7) >> 1;
  int nt = ((blockIdx.x >> 3) << 1) + (blockIdx.x & 1);
  if (nt >= 157) return;
  int n0 = nt * 64;
  int tid = threadIdx.x;

  // ---- phase 1: hsum[n] = Σ relu(Xa[src]+Xb[n]) over in-edges; states -> ninp ----
  {
    int nl = tid >> 2, part = tid & 3;
    int n = n0 + nl;
    float acc[32];
    #pragma unroll
    for (int i = 0; i < 32; i++) acc[i] = 0.f;
    if (n < Nn){
      float xbf[32];
      {
        const u16* xp = xab + ((size_t)b * Nn + n) * 256 + 128 + part * 8;
        union { uint4 v; u16 h[8]; } q0, q1, q2, q3;
        q0.v = *(const uint4*)(xp);
        q1.v = *(const uint4*)(xp + 32);
        q2.v = *(const uint4*)(xp + 64);
        q3.v = *(const uint4*)(xp + 96);
        #pragma unroll
        for (int j = 0; j < 8; j++){
          xbf[j] = b2f(q0.h[j]); xbf[8 + j] = b2f(q1.h[j]);
          xbf[16 + j] = b2f(q2.h[j]); xbf[24 + j] = b2f(q3.h[j]);
        }
      }
      int r0 = rowp[n], r1 = rowp[n + 1];
      const u16* xb0 = xab + (size_t)b * Nn * 256 + part * 8;
      for (int r = r0; r < r1; r++){
        int s = psrc[r];
        const u16* xs = xb0 + (size_t)s * 256;
        union { uint4 v; u16 h[8]; } q0, q1, q2, q3;
        q0.v = *(const uint4*)(xs);
        q1.v = *(const uint4*)(xs + 32);
        q2.v = *(const uint4*)(xs + 64);
        q3.v = *(const uint4*)(xs + 96);
        #pragma unroll
        for (int j = 0; j < 8; j++){
          float v0 = b2f(q0.h[j]) + xbf[j];
          acc[j] += v0 > 0.f ? v0 : 0.f;
          float v1 = b2f(q1.h[j]) + xbf[8 + j];
          acc[8 + j] += v1 > 0.f ? v1 : 0.f;
          float v2 = b2f(q2.h[j]) + xbf[16 + j];
          acc[16 + j] += v2 > 0.f ? v2 : 0.f;
          float v3 = b2f(q3.h[j]) + xbf[24 + j];
          acc[24 + j] += v3 > 0.f ? v3 : 0.f;
        }
      }
    }
    // write hs row (bf16, pi-space) — consumed by this wave's phase-2 MFMA.
    union { u16 h[32]; uint4 v[4]; } hb;
    #pragma unroll
    for (int i = 0; i < 32; i++) hb.h[i] = f2b(acc[i]);
    u16* hp = hsYt + nl * 136 + part * 8;
    *(uint4*)(hp)      = hb.v[0];
    *(uint4*)(hp + 32) = hb.v[1];
    *(uint4*)(hp + 64) = hb.v[2];
    *(uint4*)(hp + 96) = hb.v[3];
    // states part of ninp (same lane-contiguous pattern)
    u16* dp = ninp + nl * 200 + 64 + part * 8;
    if (n < Nn){
      const u16* sp = sbm + (((size_t)b * Nn + n) << 7) + part * 8;
      *(uint4*)(dp)      = *(const uint4*)(sp);
      *(uint4*)(dp + 32) = *(const uint4*)(sp + 32);
      *(uint4*)(dp + 64) = *(const uint4*)(sp + 64);
      *(uint4*)(dp + 96) = *(const uint4*)(sp + 96);
    } else {
      uint4 zz = {0, 0, 0, 0};
      *(uint4*)(dp)      = zz;
      *(uint4*)(dp + 32) = zz;
      *(uint4*)(dp + 64) = zz;
      *(uint4*)(dp + 96) = zz;
    }
  }
  // no barrier: wave w wrote hs/ninp rows [16w,16w+16) and reads only those below

  int w = tid >> 6, lane = tid & 63, m = lane & 15, quad = lane >> 4;
  const f32x4 z4 = {0.f, 0.f, 0.f, 0.f};

  // ---- phase 2: incoming = hs @ w2e + deg*b2e -> ninp[0:64] ----
  // hs and w2es both pi-ordered on k -> contraction unchanged.
  {
    f32x4 acc[4];
    #pragma unroll
    for (int ct = 0; ct < 4; ct++) acc[ct] = z4;
    #pragma unroll
    for (int ks = 0; ks < 4; ks++){
      bf16x8 a = *(const bf16x8*)(hsYt + (w * 16 + m) * 136 + ks * 32 + quad * 8);
      #pragma unroll
      for (int ct = 0; ct < 4; ct++){
        bf16x8 bv = *(const bf16x8*)(w2es + (((ks * 4 + quad) << 6) + ct * 16 + m) * 8);
        acc[ct] = __builtin_amdgcn_mfma_f32_16x16x32_bf16(a, bv, acc[ct], 0, 0, 0);
      }
    }
    #pragma unroll
    for (int i = 0; i < 4; i++){
      int n = n0 + w * 16 + quad * 4 + i;
      float deg = (n < Nn) ? (float)(rowp[n + 1] - rowp[n]) : 0.f;
      #pragma unroll
      for (int ct = 0; ct < 4; ct++)
        ninp[(w * 16 + quad * 4 + i) * 200 + ct * 16 + m] = f2b(acc[ct][i] + deg * b2ef[ct * 16 + m]);
    }
  }

  // ---- phase 3: node MLP ----
  f32x4 acc1[8];
  #pragma unroll
  for (int ct = 0; ct < 8; ct++) acc1[ct] = z4;
  #pragma unroll 1
  for (int ks = 0; ks < 6; ks++){
    bf16x8 a = *(const bf16x8*)(ninp + (w * 16 + m) * 200 + ks * 32 + quad * 8);
    #pragma unroll
    for (int ct = 0; ct < 8; ct++){
      bf16x8 bv = *(const bf16x8*)(w1s + (((ks * 4 + quad) << 7) + ct * 16 + m) * 8);
      acc1[ct] = __builtin_amdgcn_mfma_f32_16x16x32_bf16(a, bv, acc1[ct], 0, 0, 0);
    }
  }
  #pragma unroll
  for (int ct = 0; ct < 8; ct++){
    float bb = b1f[ct * 16 + m];
    #pragma unroll
    for (int i = 0; i < 4; i++){
      float v = acc1[ct][i] + bb;
      v = v > 0.f ? v : 0.f;
      hsYt[(w * 16 + quad * 4 + i) * 136 + ct * 16 + m] = f2b(v);
    }
  }
  f32x4 acc2[8];
  #pragma unroll
  for (int ct = 0; ct < 8; ct++) acc2[ct] = z4;
  #pragma unroll 1
  for (int ko = 0; ko < 4; ko++){
    bf16x8 a2 = *(const bf16x8*)(hsYt + (w * 16 + m) * 136 + ko * 32 + quad * 8);
    #pragma unroll
    for (int ct = 0; ct < 8; ct++){
      bf16x8 bv = *(const bf16x8*)(w2s + (((ko * 4 + quad) << 7) + ct * 16 + m) * 8);
      acc2[ct] = __builtin_amdgcn_mfma_f32_16x16x32_bf16(a2, bv, acc2[ct], 0, 0, 0);
    }
  }

  // ---- phase 4: epilogue. Old state = ninp LDS (no global read). Build new-state
  // tile in hsYt (wave-private rows). mode==0 additionally writes the sbm mirror. ----
  #pragma unroll
  for (int ct = 0; ct < 8; ct++){
    int u = ct * 16 + m;
    if (u < 126){
      float bb = b2f2[u];
      #pragma unroll
      for (int i = 0; i < 4; i++){
        int nl = w * 16 + quad * 4 + i;
        int n = n0 + nl;
        if (n < Nn){
          float old = b2f(ninp[nl * 200 + 64 + 2 + u]);
          float v = old + acc2[ct][i] + bb;
          u16 hv = f2b(v);
          if (mode == 0)
            sbm[(((size_t)b * Nn + n) << 7) + 2 + u] = hv;
          hsYt[nl * 136 + 2 + u] = hv;
        } else {
          hsYt[nl * 136 + 2 + u] = 0;
        }
      }
    }
  }
  // channels 0,1 are never updated: copy old state (0 for pad rows) from ninp
  if (m < 2){
    #pragma unroll
    for (int i = 0; i < 4; i++){
      int nl = w * 16 + quad * 4 + i;
      hsYt[nl * 136 + m] = ninp[nl * 200 + 64 + m];
    }
  }

  if (mode == 0){
    // ---- fused next-step xform: Xa/Xb = newstate @ W1e, pi-order stores ----
    // W1 staged in 16KB quarters (64 k-rows) into dead ninp region.
    #pragma unroll
    for (int half = 0; half < 2; half++){
      f32x4 xacc[8];
      #pragma unroll
      for (int ct = 0; ct < 8; ct++) xacc[ct] = z4;
      #pragma unroll
      for (int st = 0; st < 2; st++){
        __syncthreads();                       // tile/ch01 writes + prior staging reads done
        {
          const uint4* g = (const uint4*)(w1es + half * 16384 + st * 8192);
          uint4* l = (uint4*)ninp;
          #pragma unroll
          for (int i = 0; i < 4; i++) l[tid + i * 256] = g[tid + i * 256];
        }
        __syncthreads();
        #pragma unroll
        for (int lk = 0; lk < 2; lk++){
          bf16x8 a = *(const bf16x8*)(hsYt + (w * 16 + m) * 136 + st * 64 + lk * 32 + quad * 8);
          #pragma unroll
          for (int ct = 0; ct < 8; ct++){
            bf16x8 bv = *(const bf16x8*)(ninp + (((lk * 4 + quad) << 7) + ct * 16 + m) * 8);
            xacc[ct] = __builtin_amdgcn_mfma_f32_16x16x32_bf16(a, bv, xacc[ct], 0, 0, 0);
          }
        }
      }
      #pragma unroll
      for (int i = 0; i < 4; i++){
        int r = n0 + w * 16 + quad * 4 + i;
        if (r < Nn){
          union { u16 h[8]; uint4 v; } t;
          #pragma unroll
          for (int ct = 0; ct < 8; ct++)
            t.h[ct] = f2b(xacc[ct][i] + ((half == 0) ? b1ef[ct * 16 + m] : 0.f));
          *(uint4*)(xabn + ((size_t)b * Nn + r) * 256 + half * 128 + m * 8) = t.v;
        }
      }
    }
  } else {
    // ---- last step: wave-private transposed store to sswz (kg planes nt*8+2w+{0,1}) ----
    #pragma unroll
    for (int r = 0; r < 2; r++){
      int kg = nt * 8 + w * 2 + r;
      if (kg < KG){
        #pragma unroll
        for (int dd = 0; dd < 2; dd++){
          int d = dd * 64 + lane;
          union { u16 h[8]; uint4 v; } t;
          #pragma unroll
          for (int j = 0; j < 8; j++) t.h[j] = hsYt[(w * 16 + r * 8 + j) * 136 + d];
          *(uint4*)(sswz + (((size_t)b * KG + kg) * 128 + d) * 8) = t.v;
        }
      }
    }
  }
}

// 32 K-chunks; A-frags read DIRECTLY from attn. Partial sums via f32 atomicAdd
// into partsum (0.5MB, zeroed upfront). R11 lesson: LDS-staging B here
// REGRESSED (+8us: stage traffic + barrier + 2x atomics) — keep direct L2 reads.
__global__ __launch_bounds__(256) void extract2_kernel(
  const void* __restrict__ attn, const void* __restrict__ in_states,
  const u16* __restrict__ sswz, float* __restrict__ partsum)
{
  int f = detect_flag(in_states);
  int blk = blockIdx.x;
  int kc = blk & 31, qt = (blk >> 5) & 3, b = blk >> 7;
  int tid = threadIdx.x, w = tid >> 6, lane = tid & 63, m = lane & 15, quad = lane >> 4;
  int qr = qt * 4 + w, q0 = qr * 16;
  int kg0 = kc * 40;
  int nsteps = (kc == 31) ? 3 : 10;            // tail: 1240..1251 covered by 3 steps
  long arow = ((long)(b * Qq + q0 + m)) * Nn;
  const u16* ab16 = (const u16*)attn + arow;
  const float* af32 = (const float*)attn + arow;
  const u16* sbase = sswz + ((size_t)b) * KG * 1024;
  f32x4 acc[8];
  const f32x4 z4 = {0.f, 0.f, 0.f, 0.f};
  #pragma unroll
  for (int ct = 0; ct < 8; ct++) acc[ct] = z4;
  #pragma unroll 2
  for (int t = 0; t < nsteps; t++){
    int kg = kg0 + t * 4 + quad;
    int kgc = kg < KG ? kg : 0;                // clamp B-frag addr; a=0 keeps math exact
    bf16x8 a;
    if (kg < 1250){
      if (f){
        a = *(const bf16x8*)(ab16 + kg * 8);
      } else {
        const float* ap = af32 + kg * 8;
        float4 p0 = *(const float4*)ap;
        float4 p1 = *(const float4*)(ap + 4);
        a[0] = (__bf16)p0.x; a[1] = (__bf16)p0.y; a[2] = (__bf16)p0.z; a[3] = (__bf16)p0.w;
        a[4] = (__bf16)p1.x; a[5] = (__bf16)p1.y; a[6] = (__bf16)p1.z; a[7] = (__bf16)p1.w;
      }
    } else {
      #pragma unroll
      for (int j = 0; j < 8; j++) a[j] = (__bf16)0.f;
    }
    #pragma unroll
    for (int ct = 0; ct < 8; ct++){
      bf16x8 bv = *(const bf16x8*)(sbase + ((size_t)kgc * 128 + ct * 16 + m) * 8);
      acc[ct] = __builtin_amdgcn_mfma_f32_16x16x32_bf16(a, bv, acc[ct], 0, 0, 0);
    }
  }
  #pragma unroll
  for (int ct = 0; ct < 8; ct++){
    #pragma unroll
    for (int i = 0; i < 4; i++)
      atomicAdd(&partsum[(((size_t)b * Qq + q0 + quad * 4 + i) << 7) + ct * 16 + m], acc[ct][i]);
  }
}

// ---------------- finalize: out = [poses | partsum] ----------------
__global__ void final_kernel(const void* __restrict__ poses, const void* __restrict__ in_states,
                             const float* __restrict__ partsum, void* __restrict__ out)
{
  int f = detect_flag(in_states);
  const long total = (long)Bx * Qq * (Pp + Dd);
  for (long idx = (long)blockIdx.x * blockDim.x + threadIdx.x; idx < total; idx += (long)gridDim.x * blockDim.x){
    int j = (int)(idx % (Pp + Dd));
    long bq = idx / (Pp + Dd);
    float v;
    if (j < Pp){
      v = ldin(poses, bq * Pp + j, f);
    } else {
      v = partsum[(bq << 7) + (j - Pp)];
    }
    if (f) ((u16*)out)[idx] = f2b(v);
    else ((float*)out)[idx] = v;
  }
}

extern "C" void kernel_launch(void* const* d_in, const int* in_sizes, int n_in,
                              void* d_out, int out_size, void* d_ws, size_t ws_size,
                              hipStream_t stream)
{
  const void* in_states = d_in[0];
  const void* in_poses  = d_in[1];
  const void* in_attn   = d_in[2];
  const int*  in_src    = (const int*)d_in[3];
  const int*  in_snk    = (const int*)d_in[4];
  const void* in_w1e = d_in[5];  const void* in_b1e = d_in[6];
  const void* in_w2e = d_in[7];  const void* in_b2e = d_in[8];
  const void* in_w1n = d_in[9];  const void* in_b1n = d_in[10];
  const void* in_w2n = d_in[11]; const void* in_b2n = d_in[12];

  char* ws = (char*)d_ws;
  size_t off = 0;
  auto alloc = [&](size_t bytes){ size_t o = off; off = (off + bytes + 255) & ~(size_t)255; return o; };
  const size_t psumB = (size_t)Bx * Qq * Dd * 4;        // 0.5 MB
  size_t o_sb   = alloc((size_t)Bx * Nn * Dd * 2);
  size_t o_xabA = alloc((size_t)Bx * Nn * 256 * 2);     // 20.5 MB double-buffered
  size_t o_xabB = alloc((size_t)Bx * Nn * 256 * 2);
  size_t o_rowp = alloc((size_t)(Nn + 1) * 4);
  size_t o_rcnt = alloc((size_t)Nn * 2 * 4 + psumB);    // rcnt | rcnt2 | partsum: one memset
  size_t o_psrc = alloc((size_t)Ee * 4);
  size_t o_w1e  = alloc(32768 * 2);
  size_t o_w2e  = alloc(8192 * 2);
  size_t o_w1n  = alloc(24576 * 2);
  size_t o_w2n  = alloc(16384 * 2);
  size_t o_b1e  = alloc(128 * 4);
  size_t o_b2e  = alloc(64 * 4);
  size_t o_b1n  = alloc(128 * 4);
  size_t o_b2n  = alloc(128 * 4);
  size_t o_sswz = alloc((size_t)Bx * KG * 128 * 8 * 2); // 10.3 MB

  u16*   sbm   = (u16*)(ws + o_sb);
  u16*   xabA  = (u16*)(ws + o_xabA);
  u16*   xabB  = (u16*)(ws + o_xabB);
  int*   rowp  = (int*)(ws + o_rowp);
  int*   rcnt  = (int*)(ws + o_rcnt);
  int*   rcnt2 = rcnt + Nn;
  float* psum  = (float*)(ws + o_rcnt + (size_t)Nn * 2 * 4);
  int*   psrc  = (int*)(ws + o_psrc);
  u16*   w1e_s = (u16*)(ws + o_w1e);
  u16*   w2e_s = (u16*)(ws + o_w2e);
  u16*   w1n_s = (u16*)(ws + o_w1n);
  u16*   w2n_s = (u16*)(ws + o_w2n);
  float* b1e_f = (float*)(ws + o_b1e);
  float* b2e_f = (float*)(ws + o_b2e);
  float* b1n_f = (float*)(ws + o_b1n);
  float* b2n_f = (float*)(ws + o_b2n);
  u16*   sswz  = (u16*)(ws + o_sswz);

  hipMemsetAsync(rcnt, 0, (size_t)Nn * 2 * 4 + psumB, stream);  // rcnt, rcnt2, partsum
  prep_init_kernel<<<1024, 256, 0, stream>>>(in_w1e, in_b1e, in_w2e, in_b2e,
                                             in_w1n, in_b1n, in_w2n, in_b2n,
                                             in_states, in_snk,
                                             w1e_s, w2e_s, w1n_s, w2n_s,
                                             b1e_f, b2e_f, b1n_f, b2n_f,
                                             sbm, rcnt);
  scan_kernel<<<1, 1024, 0, stream>>>(rcnt, rowp);
  fill_xform_kernel<<<1257, 256, 0, stream>>>(in_src, in_snk, rowp, rcnt2, psrc,
                                              sbm, w1e_s, b1e_f, xabA);

  // step 0: gather xabA, fused xform -> xabB
  node_kernel<<<632, 256, 0, stream>>>(sbm, xabA, rowp, psrc,
                                       w2e_s, b2e_f, w1n_s, w2n_s, b1n_f, b2n_f,
                                       w1e_s, b1e_f, xabB, sswz, 0);
  // step 1: gather xabB, fused xform -> xabA
  node_kernel<<<632, 256, 0, stream>>>(sbm, xabB, rowp, psrc,
                                       w2e_s, b2e_f, w1n_s, w2n_s, b1n_f, b2n_f,
                                       w1e_s, b1e_f, xabA, sswz, 0);
  // step 2 (last): gather xabA, states -> sswz
  node_kernel<<<632, 256, 0, stream>>>(sbm, xabA, rowp, psrc,
                                       w2e_s, b2e_f, w1n_s, w2n_s, b1n_f, b2n_f,
                                       w1e_s, b1e_f, xabB, sswz, 1);

  extract2_kernel<<<512, 256, 0, stream>>>(in_attn, in_states, sswz, psum);
  final_kernel<<<540, 256, 0, stream>>>(in_poses, in_states, psum, d_out);
}